// Round 16
// baseline (201.259 us; speedup 1.0000x reference)
//
#include <hip/hip_runtime.h>
#include <math.h>

typedef __attribute__((ext_vector_type(8))) short bfrag;    // 8 bf16 = 4 VGPR
typedef __attribute__((ext_vector_type(4))) float f32x4;    // 16x16 accumulator
typedef __attribute__((ext_vector_type(16))) float f32x16;  // 32x32 accumulator
typedef __attribute__((ext_vector_type(4))) unsigned short ushort4v;

// split 8 f32 into bf16 hi + lo; (hh+hl+lh) ~ fp32. trunc8: hi only (~2^-9 rel).
__device__ __forceinline__ void split8(const float* x, bfrag& hi, bfrag& lo) {
    #pragma unroll
    for (int j = 0; j < 8; ++j) {
        unsigned xb = __float_as_uint(x[j]);
        unsigned hb = xb & 0xffff0000u;
        float lf = x[j] - __uint_as_float(hb);
        hi[j] = (short)(xb >> 16);
        lo[j] = (short)(__float_as_uint(lf) >> 16);
    }
}
__device__ __forceinline__ void trunc8(const float* x, bfrag& hi) {
    #pragma unroll
    for (int j = 0; j < 8; ++j) hi[j] = (short)(__float_as_uint(x[j]) >> 16);
}

// ---------------- front: conv1 + im2col fused, one block per batch element.
__global__ __launch_bounds__(256) void front_kernel(
    const float* __restrict__ x, const float* __restrict__ w1,
    const float* __restrict__ b1, float* __restrict__ B2) {
    __shared__ float xl[4032];
    __shared__ float wl[3456];
    __shared__ float hl[3744];
    int b = blockIdx.x, tid = threadIdx.x;
    const float* xb = x + (size_t)b * 4032;
    #pragma unroll
    for (int i = 0; i < 4; ++i) {
        int idx = tid + 256 * i;
        if (idx < 1008) *(float4*)(xl + idx * 4) = *(const float4*)(xb + idx * 4);
        if (idx < 864)  *(float4*)(wl + idx * 4) = *(const float4*)(w1 + idx * 4);
    }
    __syncthreads();
    for (int idx = tid; idx < 3744; idx += 256) {
        int oc = idx / 117, r = idx % 117;
        int oh = r / 13, ow = r % 13;
        float acc = b1[oc];
        #pragma unroll
        for (int ic = 0; ic < 3; ++ic) {
            const float* xc = xl + ic * 1344 + (oh * 3) * 42 + ow * 3;
            const float* wc = wl + (oc * 3 + ic) * 36;
            #pragma unroll
            for (int kh = 0; kh < 6; ++kh)
                #pragma unroll
                for (int kw = 0; kw < 6; ++kw)
                    acc += xc[kh * 42 + kw] * wc[kh * 6 + kw];
        }
        hl[idx] = fmaxf(acc, 0.f);
    }
    __syncthreads();
    for (int f = tid; f < 864; f += 256) {     // (ko, s)
        int ko = f / 24, s = f % 24;
        int h = s / 6, w = s % 6;
        float o8[8];
        #pragma unroll
        for (int j = 0; j < 8; ++j) {
            int k = ko * 8 + j;
            int ic = k / 9, rr = k % 9;
            int kh = rr / 3, kw = rr % 3;
            o8[j] = hl[ic * 117 + (2 * h + kh) * 13 + (2 * w + kw)];
        }
        float* dst = B2 + ((size_t)ko * 3072 + b * 24 + s) * 8;
        *(float4*)dst = *(const float4*)o8;
        *(float4*)(dst + 4) = *(const float4*)(o8 + 4);
    }
}

// ---------------- pc GEMM (MFMA) + bias + squash -> u2[i][dh][b][4]
__global__ __launch_bounds__(256) void pc_gemm_kernel(
    const float* __restrict__ wpc, const float* __restrict__ bias,
    const float* __restrict__ B2, float* __restrict__ u2) {
    int wv = threadIdx.x >> 6;
    int l = threadIdx.x & 63;
    int q = l >> 4, r16 = l & 15;
    int c2t = blockIdx.y * 4 + wv;
    int n0 = blockIdx.x * 16;
    f32x4 acc = {0.f, 0.f, 0.f, 0.f};
    const float* ap0 = wpc + (size_t)(c2t * 16 + r16) * 288 + q * 8;
    const float* bp0 = B2 + ((size_t)q * 3072 + n0 + r16) * 8;
    #pragma unroll
    for (int ks = 0; ks < 9; ++ks) {
        float av[8], bv[8];
        *(float4*)av = *(const float4*)(ap0 + ks * 32);
        *(float4*)(av + 4) = *(const float4*)(ap0 + ks * 32 + 4);
        *(float4*)bv = *(const float4*)(bp0 + (size_t)ks * 98304);
        *(float4*)(bv + 4) = *(const float4*)(bp0 + (size_t)ks * 98304 + 4);
        bfrag ahi, alo, bhi, blo;
        split8(av, ahi, alo);
        split8(bv, bhi, blo);
        acc = __builtin_amdgcn_mfma_f32_16x16x32_bf16(ahi, bhi, acc, 0, 0, 0);
        acc = __builtin_amdgcn_mfma_f32_16x16x32_bf16(ahi, blo, acc, 0, 0, 0);
        acc = __builtin_amdgcn_mfma_f32_16x16x32_bf16(alo, bhi, acc, 0, 0, 0);
    }
    int n = n0 + r16;
    int b = n / 24, s = n % 24;
    float vals[4], n2[4];
    #pragma unroll
    for (int r = 0; r < 4; ++r) {
        float xv = acc[r] + bias[c2t * 16 + q * 4 + r];
        vals[r] = xv;
        n2[r] = xv * xv;
    }
    #pragma unroll
    for (int r = 0; r < 4; ++r) {
        n2[r] += __shfl_xor(n2[r], 1, 64);
        n2[r] += __shfl_xor(n2[r], 2, 64);
        n2[r] += __shfl_xor(n2[r], 4, 64);
    }
    #pragma unroll
    for (int r = 0; r < 4; ++r) {
        int c2 = c2t * 16 + q * 4 + r;
        int cap = c2 * 3 + (s >> 3);
        int d = s & 7;
        float nr = sqrtf(n2[r]);
        u2[((size_t)(cap * 2 + (d >> 2)) * 128 + b) * 4 + (d & 3)]
            = vals[r] * nr / (1.f + n2[r]);
    }
}

// ---------------- zsum: zsum[i,b] = sum_o exp(blog[o,i,b]); 2 lanes per (i,b)
__global__ __launch_bounds__(256) void zsum_kernel(
    const float* __restrict__ blog, float* __restrict__ zsum) {
    int i = blockIdx.x;
    int tid = threadIdx.x;
    int b = tid >> 1, oh = tid & 1;
    const float* src = blog + (size_t)oh * 32 * 98304 + (size_t)i * 128 + b;
    float sum = 0.f;
    #pragma unroll
    for (int o = 0; o < 32; ++o) sum += __expf(src[(size_t)o * 98304]);
    sum += __shfl_xor(sum, 1, 64);
    if (!oh) zsum[i * 128 + b] = sum;
}

// ---------------- s-pass: 64-cap tiles; W pre-split to bf16 hi/lo in LDS.
// Output layout s_part[it][o][b][k] (o-major for fused consumer reads).
template <bool UNIFORM>
__global__ __launch_bounds__(256, 4) void spass_kernel(
    const float* __restrict__ W, const float* __restrict__ u2,
    const float* __restrict__ blog, const float* __restrict__ zsum,
    float* __restrict__ s_part) {
    int o = blockIdx.x;
    int it = blockIdx.y;       // 0..11 (64 caps)
    int tid = threadIdx.x;
    int wv = tid >> 6;
    int l = tid & 63;
    int q = l >> 4, r16 = l & 15;
    int i0 = it * 64;
    __shared__ unsigned short whi[64 * 136];
    __shared__ unsigned short wlo[64 * 136];

    float4 ua[3][2][2];
    float blv[3][2], zv[3][2];
    auto issue = [&](int s, int buf) {
        int cap = i0 + s * 4 + q;
        #pragma unroll
        for (int m = 0; m < 2; ++m) {
            int b = wv * 32 + m * 16 + r16;
            ua[buf][m][0] = *(const float4*)(u2 + ((size_t)(cap * 2 + 0) * 128 + b) * 4);
            ua[buf][m][1] = *(const float4*)(u2 + ((size_t)(cap * 2 + 1) * 128 + b) * 4);
            if (!UNIFORM) {
                blv[buf][m] = blog[((size_t)o * 768 + cap) * 128 + b];
                zv[buf][m]  = zsum[cap * 128 + b];
            }
        }
    };

    issue(0, 0);
    issue(1, 1);
    #pragma unroll
    for (int itr = 0; itr < 8; ++itr) {
        int F = tid + 256 * itr;     // 0..2047 float4s
        int cap = F >> 5, slot = F & 31;
        float4 t4 = *(const float4*)(W + ((size_t)(i0 + cap) * 64 + o) * 128 + slot * 4);
        ushort4v h4, l4;
        float tf[4] = {t4.x, t4.y, t4.z, t4.w};
        #pragma unroll
        for (int j = 0; j < 4; ++j) {
            unsigned xb = __float_as_uint(tf[j]);
            float lf = tf[j] - __uint_as_float(xb & 0xffff0000u);
            h4[j] = (unsigned short)(xb >> 16);
            l4[j] = (unsigned short)(__float_as_uint(lf) >> 16);
        }
        *(ushort4v*)(whi + cap * 136 + slot * 4) = h4;
        *(ushort4v*)(wlo + cap * 136 + slot * 4) = l4;
    }
    __syncthreads();

    f32x4 acc0 = {0.f, 0.f, 0.f, 0.f};
    f32x4 acc1 = {0.f, 0.f, 0.f, 0.f};
    #pragma unroll
    for (int s = 0; s < 16; ++s) {
        int cur = s % 3;
        if (s < 14) issue(s + 2, (s + 2) % 3);
        int wrow = (s * 4 + q) * 136 + r16 * 8;
        bfrag bhi = *(const bfrag*)(whi + wrow);
        bfrag blo = *(const bfrag*)(wlo + wrow);
        #pragma unroll
        for (int m = 0; m < 2; ++m) {
            float uv[8];
            *(float4*)(uv) = ua[cur][m][0];
            *(float4*)(uv + 4) = ua[cur][m][1];
            if (!UNIFORM) {
                float c = __expf(blv[cur][m]) / zv[cur][m];
                #pragma unroll
                for (int j = 0; j < 8; ++j) uv[j] *= c;
            }
            bfrag ahi;
            trunc8(uv, ahi);
            if (m == 0) {
                acc0 = __builtin_amdgcn_mfma_f32_16x16x32_bf16(ahi, bhi, acc0, 0, 0, 0);
                acc0 = __builtin_amdgcn_mfma_f32_16x16x32_bf16(ahi, blo, acc0, 0, 0, 0);
            } else {
                acc1 = __builtin_amdgcn_mfma_f32_16x16x32_bf16(ahi, bhi, acc1, 0, 0, 0);
                acc1 = __builtin_amdgcn_mfma_f32_16x16x32_bf16(ahi, blo, acc1, 0, 0, 0);
            }
        }
    }
    // store: s_part[it][o][b][k]
    #pragma unroll
    for (int reg = 0; reg < 4; ++reg) {
        int b0 = wv * 32 + q * 4 + reg;
        s_part[(size_t)it * 131072 + o * 2048 + b0 * 16 + r16] = acc0[reg];
        s_part[(size_t)it * 131072 + o * 2048 + (b0 + 16) * 16 + r16] = acc1[reg];
    }
}

// ---------------- final: reduce 12 partials + squash -> out[b][o][k]
__global__ __launch_bounds__(256) void squashv_final(
    const float* __restrict__ s_part, float* __restrict__ out) {
    int idx = blockIdx.x * 256 + threadIdx.x;  // b*1024 + o*16 + k
    int k = idx & 15, o = (idx >> 4) & 63, b = idx >> 10;
    const float* sp = s_part + o * 2048 + b * 16 + k;
    float acc = 0.f;
    #pragma unroll
    for (int it = 0; it < 12; ++it) acc += sp[(size_t)it * 131072];
    float n2 = acc * acc;
    n2 += __shfl_xor(n2, 1, 64);
    n2 += __shfl_xor(n2, 2, 64);
    n2 += __shfl_xor(n2, 4, 64);
    n2 += __shfl_xor(n2, 8, 64);
    float n = sqrtf(n2);
    out[idx] = acc * n / (1.f + n2);
}

// ---------------- b-pass (+ fused v reduce/squash from s_part, in registers):
// v[b][k] for this o = squash(scale * sum_it s_part[it][o][b][k]); kh-halves
// complete the k-norm via shfl_xor(32). Then blog (+)= sum_d u*(W x v).
template <bool ACCUM>
__global__ __launch_bounds__(256, 4) void bpass_kernel(
    const float* __restrict__ W, const float* __restrict__ u2,
    const float* __restrict__ s_part, float* __restrict__ blog, float scale) {
    int o = blockIdx.x, it = blockIdx.y;   // it: 0..23 (32 caps)
    int tid = threadIdx.x;
    int wv = tid >> 6;
    int l = tid & 63;
    int r = l & 31;
    int kh = l >> 5;
    int capB = it * 32;
    __shared__ float wl[32 * 164];
    #pragma unroll
    for (int itr = 0; itr < 4; ++itr) {
        int F = tid + 256 * itr;
        int cap = F >> 5, slot = F & 31;
        int k = slot >> 1, dh = slot & 1;
        float4 t4 = *(const float4*)(W + ((size_t)(capB + cap) * 64 + o) * 128 + k * 8 + dh * 4);
        float* dst = wl + cap * 164 + (dh * 4) * 20 + k;
        dst[0] = t4.x; dst[20] = t4.y; dst[40] = t4.z; dst[60] = t4.w;
    }
    // fused squashv: per nt, reduce 12 partials for (b = nt*32+r, k = kh*8..+8)
    bfrag vhi[4], vlo[4];
    #pragma unroll
    for (int nt = 0; nt < 4; ++nt) {
        int b = nt * 32 + r;
        const float* sp = s_part + o * 2048 + b * 16 + kh * 8;
        float a8[8] = {0.f, 0.f, 0.f, 0.f, 0.f, 0.f, 0.f, 0.f};
        #pragma unroll
        for (int it2 = 0; it2 < 12; ++it2) {
            float4 p0 = *(const float4*)(sp + (size_t)it2 * 131072);
            float4 p1 = *(const float4*)(sp + (size_t)it2 * 131072 + 4);
            a8[0] += p0.x; a8[1] += p0.y; a8[2] += p0.z; a8[3] += p0.w;
            a8[4] += p1.x; a8[5] += p1.y; a8[6] += p1.z; a8[7] += p1.w;
        }
        float n2p = 0.f;
        #pragma unroll
        for (int j = 0; j < 8; ++j) { a8[j] *= scale; n2p += a8[j] * a8[j]; }
        float n2 = n2p + __shfl_xor(n2p, 32, 64);
        float nr = sqrtf(n2);
        float sc = nr / (1.f + n2);
        #pragma unroll
        for (int j = 0; j < 8; ++j) a8[j] *= sc;
        split8(a8, vhi[nt], vlo[nt]);
    }
    __syncthreads();
    #pragma unroll
    for (int mt = 0; mt < 2; ++mt) {
        int cl = wv * 8 + mt * 4 + (r >> 3);
        const float* ap = wl + cl * 164 + (r & 7) * 20 + kh * 8;
        float a8[8];
        *(float4*)(a8) = *(const float4*)ap;
        *(float4*)(a8 + 4) = *(const float4*)(ap + 4);
        int capg = capB + wv * 8 + mt * 4;
        int gw = kh * 2;
        float prevv[4][2];
        if (ACCUM) {
            #pragma unroll
            for (int nt = 0; nt < 4; ++nt) {
                int b = nt * 32 + r;
                #pragma unroll
                for (int gg = 0; gg < 2; ++gg)
                    prevv[nt][gg] = blog[((size_t)o * 768 + capg + gw + gg) * 128 + b];
            }
        }
        float4 u4b[2][4];
        #pragma unroll
        for (int g = 0; g < 4; ++g)
            u4b[0][g] = *(const float4*)(u2 + ((size_t)((capg + g) * 2 + kh) * 128 + r) * 4);
        bfrag ahi, alo;
        split8(a8, ahi, alo);
        #pragma unroll
        for (int nt = 0; nt < 4; ++nt) {
            int cur = nt & 1;
            if (nt < 3) {
                int bn = (nt + 1) * 32 + r;
                #pragma unroll
                for (int g = 0; g < 4; ++g)
                    u4b[cur ^ 1][g] = *(const float4*)(u2 + ((size_t)((capg + g) * 2 + kh) * 128 + bn) * 4);
            }
            int b = nt * 32 + r;
            f32x16 acc;
            #pragma unroll
            for (int z = 0; z < 16; ++z) acc[z] = 0.f;
            acc = __builtin_amdgcn_mfma_f32_32x32x16_bf16(ahi, vhi[nt], acc, 0, 0, 0);
            acc = __builtin_amdgcn_mfma_f32_32x32x16_bf16(ahi, vlo[nt], acc, 0, 0, 0);
            acc = __builtin_amdgcn_mfma_f32_32x32x16_bf16(alo, vhi[nt], acc, 0, 0, 0);
            float full[4];
            #pragma unroll
            for (int g = 0; g < 4; ++g) {
                float part = u4b[cur][g].x * acc[g * 4 + 0] + u4b[cur][g].y * acc[g * 4 + 1]
                           + u4b[cur][g].z * acc[g * 4 + 2] + u4b[cur][g].w * acc[g * 4 + 3];
                full[g] = part + __shfl_xor(part, 32, 64);
            }
            #pragma unroll
            for (int gg = 0; gg < 2; ++gg) {
                int g = gw + gg;
                size_t bi = ((size_t)o * 768 + capg + g) * 128 + b;
                blog[bi] = (ACCUM ? prevv[nt][gg] : 0.f) + full[g];
            }
        }
    }
}

extern "C" void kernel_launch(void* const* d_in, const int* in_sizes, int n_in,
                              void* d_out, int out_size, void* d_ws, size_t ws_size,
                              hipStream_t stream) {
    const float* x  = (const float*)d_in[0];
    const float* w1 = (const float*)d_in[1];
    const float* b1 = (const float*)d_in[2];
    const float* wp = (const float*)d_in[3];
    const float* bp = (const float*)d_in[4];
    const float* W  = (const float*)d_in[5];
    float* out = (float*)d_out;
    float* ws = (float*)d_ws;

    float* u2     = ws;                  // 786432
    float* blog   = ws + 786432;         // 6291456
    float* zsum   = ws + 7077888;        // 98304
    float* s_part = ws + 7405568;        // 12 * 131072
    float* B2     = s_part;              // 884736, dead before spass writes s_part

    front_kernel<<<128, 256, 0, stream>>>(x, w1, b1, B2);
    pc_gemm_kernel<<<dim3(192, 4), 256, 0, stream>>>(wp, bp, B2, u2);

    // iteration 0 (uniform c; 1/64 folded into bpass's fused squash scale)
    spass_kernel<true><<<dim3(64, 12), 256, 0, stream>>>(W, u2, nullptr, nullptr, s_part);
    bpass_kernel<false><<<dim3(64, 24), 256, 0, stream>>>(W, u2, s_part, blog, 1.f / 64.f);

    // iteration 1
    zsum_kernel<<<768, 256, 0, stream>>>(blog, zsum);
    spass_kernel<false><<<dim3(64, 12), 256, 0, stream>>>(W, u2, blog, zsum, s_part);
    bpass_kernel<true><<<dim3(64, 24), 256, 0, stream>>>(W, u2, s_part, blog, 1.f);

    // final
    zsum_kernel<<<768, 256, 0, stream>>>(blog, zsum);
    spass_kernel<false><<<dim3(64, 12), 256, 0, stream>>>(W, u2, blog, zsum, s_part);
    squashv_final<<<512, 256, 0, stream>>>(s_part, out);
}

// Round 17
// 142.047 us; speedup vs baseline: 1.4169x; 1.4169x over previous
//
#include <hip/hip_runtime.h>
#include <math.h>

typedef __attribute__((ext_vector_type(8))) short bfrag;    // 8 bf16 = 4 VGPR
typedef __attribute__((ext_vector_type(4))) float f32x4;    // 16x16 accumulator
typedef __attribute__((ext_vector_type(16))) float f32x16;  // 32x32 accumulator
typedef __attribute__((ext_vector_type(4))) unsigned short ushort4v;

// split 8 f32 into bf16 hi + lo; (hh+hl+lh) ~ fp32. trunc8: hi only (~2^-9 rel).
__device__ __forceinline__ void split8(const float* x, bfrag& hi, bfrag& lo) {
    #pragma unroll
    for (int j = 0; j < 8; ++j) {
        unsigned xb = __float_as_uint(x[j]);
        unsigned hb = xb & 0xffff0000u;
        float lf = x[j] - __uint_as_float(hb);
        hi[j] = (short)(xb >> 16);
        lo[j] = (short)(__float_as_uint(lf) >> 16);
    }
}
__device__ __forceinline__ void trunc8(const float* x, bfrag& hi) {
    #pragma unroll
    for (int j = 0; j < 8; ++j) hi[j] = (short)(__float_as_uint(x[j]) >> 16);
}

// ---------------- front: conv1 + im2col fused, one block per batch element.
__global__ __launch_bounds__(256) void front_kernel(
    const float* __restrict__ x, const float* __restrict__ w1,
    const float* __restrict__ b1, float* __restrict__ B2) {
    __shared__ float xl[4032];
    __shared__ float wl[3456];
    __shared__ float hl[3744];
    int b = blockIdx.x, tid = threadIdx.x;
    const float* xb = x + (size_t)b * 4032;
    #pragma unroll
    for (int i = 0; i < 4; ++i) {
        int idx = tid + 256 * i;
        if (idx < 1008) *(float4*)(xl + idx * 4) = *(const float4*)(xb + idx * 4);
        if (idx < 864)  *(float4*)(wl + idx * 4) = *(const float4*)(w1 + idx * 4);
    }
    __syncthreads();
    for (int idx = tid; idx < 3744; idx += 256) {
        int oc = idx / 117, r = idx % 117;
        int oh = r / 13, ow = r % 13;
        float acc = b1[oc];
        #pragma unroll
        for (int ic = 0; ic < 3; ++ic) {
            const float* xc = xl + ic * 1344 + (oh * 3) * 42 + ow * 3;
            const float* wc = wl + (oc * 3 + ic) * 36;
            #pragma unroll
            for (int kh = 0; kh < 6; ++kh)
                #pragma unroll
                for (int kw = 0; kw < 6; ++kw)
                    acc += xc[kh * 42 + kw] * wc[kh * 6 + kw];
        }
        hl[idx] = fmaxf(acc, 0.f);
    }
    __syncthreads();
    for (int f = tid; f < 864; f += 256) {     // (ko, s)
        int ko = f / 24, s = f % 24;
        int h = s / 6, w = s % 6;
        float o8[8];
        #pragma unroll
        for (int j = 0; j < 8; ++j) {
            int k = ko * 8 + j;
            int ic = k / 9, rr = k % 9;
            int kh = rr / 3, kw = rr % 3;
            o8[j] = hl[ic * 117 + (2 * h + kh) * 13 + (2 * w + kw)];
        }
        float* dst = B2 + ((size_t)ko * 3072 + b * 24 + s) * 8;
        *(float4*)dst = *(const float4*)o8;
        *(float4*)(dst + 4) = *(const float4*)(o8 + 4);
    }
}

// ---------------- pc GEMM (MFMA) + bias + squash -> u2[i][dh][b][4]
__global__ __launch_bounds__(256) void pc_gemm_kernel(
    const float* __restrict__ wpc, const float* __restrict__ bias,
    const float* __restrict__ B2, float* __restrict__ u2) {
    int wv = threadIdx.x >> 6;
    int l = threadIdx.x & 63;
    int q = l >> 4, r16 = l & 15;
    int c2t = blockIdx.y * 4 + wv;
    int n0 = blockIdx.x * 16;
    f32x4 acc = {0.f, 0.f, 0.f, 0.f};
    const float* ap0 = wpc + (size_t)(c2t * 16 + r16) * 288 + q * 8;
    const float* bp0 = B2 + ((size_t)q * 3072 + n0 + r16) * 8;
    #pragma unroll
    for (int ks = 0; ks < 9; ++ks) {
        float av[8], bv[8];
        *(float4*)av = *(const float4*)(ap0 + ks * 32);
        *(float4*)(av + 4) = *(const float4*)(ap0 + ks * 32 + 4);
        *(float4*)bv = *(const float4*)(bp0 + (size_t)ks * 98304);
        *(float4*)(bv + 4) = *(const float4*)(bp0 + (size_t)ks * 98304 + 4);
        bfrag ahi, alo, bhi, blo;
        split8(av, ahi, alo);
        split8(bv, bhi, blo);
        acc = __builtin_amdgcn_mfma_f32_16x16x32_bf16(ahi, bhi, acc, 0, 0, 0);
        acc = __builtin_amdgcn_mfma_f32_16x16x32_bf16(ahi, blo, acc, 0, 0, 0);
        acc = __builtin_amdgcn_mfma_f32_16x16x32_bf16(alo, bhi, acc, 0, 0, 0);
    }
    int n = n0 + r16;
    int b = n / 24, s = n % 24;
    float vals[4], n2[4];
    #pragma unroll
    for (int r = 0; r < 4; ++r) {
        float xv = acc[r] + bias[c2t * 16 + q * 4 + r];
        vals[r] = xv;
        n2[r] = xv * xv;
    }
    #pragma unroll
    for (int r = 0; r < 4; ++r) {
        n2[r] += __shfl_xor(n2[r], 1, 64);
        n2[r] += __shfl_xor(n2[r], 2, 64);
        n2[r] += __shfl_xor(n2[r], 4, 64);
    }
    #pragma unroll
    for (int r = 0; r < 4; ++r) {
        int c2 = c2t * 16 + q * 4 + r;
        int cap = c2 * 3 + (s >> 3);
        int d = s & 7;
        float nr = sqrtf(n2[r]);
        u2[((size_t)(cap * 2 + (d >> 2)) * 128 + b) * 4 + (d & 3)]
            = vals[r] * nr / (1.f + n2[r]);
    }
}

// ---------------- zsum: zsum[i,b] = sum_o exp(blog[o,i,b]); 2 lanes per (i,b)
__global__ __launch_bounds__(256) void zsum_kernel(
    const float* __restrict__ blog, float* __restrict__ zsum) {
    int i = blockIdx.x;
    int tid = threadIdx.x;
    int b = tid >> 1, oh = tid & 1;
    const float* src = blog + (size_t)oh * 32 * 98304 + (size_t)i * 128 + b;
    float sum = 0.f;
    #pragma unroll
    for (int o = 0; o < 32; ++o) sum += __expf(src[(size_t)o * 98304]);
    sum += __shfl_xor(sum, 1, 64);
    if (!oh) zsum[i * 128 + b] = sum;
}

// ---------------- s-pass: 64-cap tiles; W pre-split to bf16 hi/lo in LDS.
template <bool UNIFORM>
__global__ __launch_bounds__(256, 4) void spass_kernel(
    const float* __restrict__ W, const float* __restrict__ u2,
    const float* __restrict__ blog, const float* __restrict__ zsum,
    float* __restrict__ s_part) {
    int o = blockIdx.x;
    int it = blockIdx.y;       // 0..11 (64 caps)
    int tid = threadIdx.x;
    int wv = tid >> 6;
    int l = tid & 63;
    int q = l >> 4, r16 = l & 15;
    int i0 = it * 64;
    __shared__ unsigned short whi[64 * 136];
    __shared__ unsigned short wlo[64 * 136];

    float4 ua[3][2][2];
    float blv[3][2], zv[3][2];
    auto issue = [&](int s, int buf) {
        int cap = i0 + s * 4 + q;
        #pragma unroll
        for (int m = 0; m < 2; ++m) {
            int b = wv * 32 + m * 16 + r16;
            ua[buf][m][0] = *(const float4*)(u2 + ((size_t)(cap * 2 + 0) * 128 + b) * 4);
            ua[buf][m][1] = *(const float4*)(u2 + ((size_t)(cap * 2 + 1) * 128 + b) * 4);
            if (!UNIFORM) {
                blv[buf][m] = blog[((size_t)o * 768 + cap) * 128 + b];
                zv[buf][m]  = zsum[cap * 128 + b];
            }
        }
    };

    issue(0, 0);
    issue(1, 1);
    #pragma unroll
    for (int itr = 0; itr < 8; ++itr) {
        int F = tid + 256 * itr;     // 0..2047 float4s
        int cap = F >> 5, slot = F & 31;
        float4 t4 = *(const float4*)(W + ((size_t)(i0 + cap) * 64 + o) * 128 + slot * 4);
        ushort4v h4, l4;
        float tf[4] = {t4.x, t4.y, t4.z, t4.w};
        #pragma unroll
        for (int j = 0; j < 4; ++j) {
            unsigned xb = __float_as_uint(tf[j]);
            float lf = tf[j] - __uint_as_float(xb & 0xffff0000u);
            h4[j] = (unsigned short)(xb >> 16);
            l4[j] = (unsigned short)(__float_as_uint(lf) >> 16);
        }
        *(ushort4v*)(whi + cap * 136 + slot * 4) = h4;
        *(ushort4v*)(wlo + cap * 136 + slot * 4) = l4;
    }
    __syncthreads();

    f32x4 acc0 = {0.f, 0.f, 0.f, 0.f};
    f32x4 acc1 = {0.f, 0.f, 0.f, 0.f};
    #pragma unroll
    for (int s = 0; s < 16; ++s) {
        int cur = s % 3;
        if (s < 14) issue(s + 2, (s + 2) % 3);
        int wrow = (s * 4 + q) * 136 + r16 * 8;
        bfrag bhi = *(const bfrag*)(whi + wrow);
        bfrag blo = *(const bfrag*)(wlo + wrow);
        #pragma unroll
        for (int m = 0; m < 2; ++m) {
            float uv[8];
            *(float4*)(uv) = ua[cur][m][0];
            *(float4*)(uv + 4) = ua[cur][m][1];
            if (!UNIFORM) {
                float c = __expf(blv[cur][m]) / zv[cur][m];
                #pragma unroll
                for (int j = 0; j < 8; ++j) uv[j] *= c;
            }
            bfrag ahi;
            trunc8(uv, ahi);
            if (m == 0) {
                acc0 = __builtin_amdgcn_mfma_f32_16x16x32_bf16(ahi, bhi, acc0, 0, 0, 0);
                acc0 = __builtin_amdgcn_mfma_f32_16x16x32_bf16(ahi, blo, acc0, 0, 0, 0);
            } else {
                acc1 = __builtin_amdgcn_mfma_f32_16x16x32_bf16(ahi, bhi, acc1, 0, 0, 0);
                acc1 = __builtin_amdgcn_mfma_f32_16x16x32_bf16(ahi, blo, acc1, 0, 0, 0);
            }
        }
    }
    #pragma unroll
    for (int reg = 0; reg < 4; ++reg) {
        int b0 = wv * 32 + q * 4 + reg;
        s_part[(((size_t)it * 128 + b0) * 64 + o) * 16 + r16] = acc0[reg];
        s_part[(((size_t)it * 128 + b0 + 16) * 64 + o) * 16 + r16] = acc1[reg];
    }
}

// ---------------- reduce 12 partials + squash -> v ([b][o][k] or [o][b][k])
template <bool TRANSPOSED>
__global__ __launch_bounds__(256) void squashv_kernel(
    const float* __restrict__ s_part, float* __restrict__ v, float scale) {
    int idx = blockIdx.x * 256 + threadIdx.x;
    float acc = 0.f;
    #pragma unroll
    for (int it = 0; it < 12; ++it) acc += s_part[(size_t)it * 131072 + idx];
    acc *= scale;
    float n2 = acc * acc;
    n2 += __shfl_xor(n2, 1, 64);
    n2 += __shfl_xor(n2, 2, 64);
    n2 += __shfl_xor(n2, 4, 64);
    n2 += __shfl_xor(n2, 8, 64);
    float n = sqrtf(n2);
    float val = acc * n / (1.f + n2);
    if (TRANSPOSED) {
        int k = idx & 15, o = (idx >> 4) & 63, b = idx >> 10;
        v[((size_t)o * 128 + b) * 16 + k] = val;
    } else {
        v[idx] = val;
    }
}

// ---------------- b-pass: blog (+)= sum_d u*(W x v); v truncated (2-term MFMA)
template <bool ACCUM>
__global__ __launch_bounds__(256, 4) void bpass_kernel(
    const float* __restrict__ W, const float* __restrict__ u2,
    const float* __restrict__ v_t, float* __restrict__ blog) {
    int o = blockIdx.x, it = blockIdx.y;   // it: 0..23 (32 caps)
    int tid = threadIdx.x;
    int wv = tid >> 6;
    int l = tid & 63;
    int r = l & 31;
    int kh = l >> 5;
    int capB = it * 32;
    __shared__ float wl[32 * 164];
    #pragma unroll
    for (int itr = 0; itr < 4; ++itr) {
        int F = tid + 256 * itr;
        int cap = F >> 5, slot = F & 31;
        int k = slot >> 1, dh = slot & 1;
        float4 t4 = *(const float4*)(W + ((size_t)(capB + cap) * 64 + o) * 128 + k * 8 + dh * 4);
        float* dst = wl + cap * 164 + (dh * 4) * 20 + k;
        dst[0] = t4.x; dst[20] = t4.y; dst[40] = t4.z; dst[60] = t4.w;
    }
    bfrag vt[4];
    #pragma unroll
    for (int nt = 0; nt < 4; ++nt) {
        const float* vp = v_t + ((size_t)o * 128 + nt * 32 + r) * 16 + kh * 8;
        float vv8[8];
        *(float4*)(vv8) = *(const float4*)vp;
        *(float4*)(vv8 + 4) = *(const float4*)(vp + 4);
        trunc8(vv8, vt[nt]);
    }
    __syncthreads();
    #pragma unroll
    for (int mt = 0; mt < 2; ++mt) {
        int cl = wv * 8 + mt * 4 + (r >> 3);
        const float* ap = wl + cl * 164 + (r & 7) * 20 + kh * 8;
        float a8[8];
        *(float4*)(a8) = *(const float4*)ap;
        *(float4*)(a8 + 4) = *(const float4*)(ap + 4);
        int capg = capB + wv * 8 + mt * 4;
        int gw = kh * 2;
        float prevv[4][2];
        if (ACCUM) {
            #pragma unroll
            for (int nt = 0; nt < 4; ++nt) {
                int b = nt * 32 + r;
                #pragma unroll
                for (int gg = 0; gg < 2; ++gg)
                    prevv[nt][gg] = blog[((size_t)o * 768 + capg + gw + gg) * 128 + b];
            }
        }
        float4 u4b[2][4];
        #pragma unroll
        for (int g = 0; g < 4; ++g)
            u4b[0][g] = *(const float4*)(u2 + ((size_t)((capg + g) * 2 + kh) * 128 + r) * 4);
        bfrag ahi, alo;
        split8(a8, ahi, alo);
        #pragma unroll
        for (int nt = 0; nt < 4; ++nt) {
            int cur = nt & 1;
            if (nt < 3) {
                int bn = (nt + 1) * 32 + r;
                #pragma unroll
                for (int g = 0; g < 4; ++g)
                    u4b[cur ^ 1][g] = *(const float4*)(u2 + ((size_t)((capg + g) * 2 + kh) * 128 + bn) * 4);
            }
            int b = nt * 32 + r;
            f32x16 acc;
            #pragma unroll
            for (int z = 0; z < 16; ++z) acc[z] = 0.f;
            acc = __builtin_amdgcn_mfma_f32_32x32x16_bf16(ahi, vt[nt], acc, 0, 0, 0);
            acc = __builtin_amdgcn_mfma_f32_32x32x16_bf16(alo, vt[nt], acc, 0, 0, 0);
            float full[4];
            #pragma unroll
            for (int g = 0; g < 4; ++g) {
                float part = u4b[cur][g].x * acc[g * 4 + 0] + u4b[cur][g].y * acc[g * 4 + 1]
                           + u4b[cur][g].z * acc[g * 4 + 2] + u4b[cur][g].w * acc[g * 4 + 3];
                full[g] = part + __shfl_xor(part, 32, 64);
            }
            #pragma unroll
            for (int gg = 0; gg < 2; ++gg) {
                int g = gw + gg;
                size_t bi = ((size_t)o * 768 + capg + g) * 128 + b;
                blog[bi] = (ACCUM ? prevv[nt][gg] : 0.f) + full[g];
            }
        }
    }
}

extern "C" void kernel_launch(void* const* d_in, const int* in_sizes, int n_in,
                              void* d_out, int out_size, void* d_ws, size_t ws_size,
                              hipStream_t stream) {
    const float* x  = (const float*)d_in[0];
    const float* w1 = (const float*)d_in[1];
    const float* b1 = (const float*)d_in[2];
    const float* wp = (const float*)d_in[3];
    const float* bp = (const float*)d_in[4];
    const float* W  = (const float*)d_in[5];
    float* out = (float*)d_out;
    float* ws = (float*)d_ws;

    float* u2     = ws;                  // 786432
    float* blog   = ws + 786432;         // 6291456
    float* zsum   = ws + 7077888;        // 98304
    float* v      = ws + 7274496;        // 131072
    float* s_part = ws + 7405568;        // 12 * 131072
    float* B2     = s_part;              // 884736, dead before spass writes s_part

    front_kernel<<<128, 256, 0, stream>>>(x, w1, b1, B2);
    pc_gemm_kernel<<<dim3(192, 4), 256, 0, stream>>>(wp, bp, B2, u2);

    // iteration 0: c uniform (1/64 folded into squash scale)
    spass_kernel<true><<<dim3(64, 12), 256, 0, stream>>>(W, u2, nullptr, nullptr, s_part);
    squashv_kernel<true><<<512, 256, 0, stream>>>(s_part, v, 1.f / 64.f);
    bpass_kernel<false><<<dim3(64, 24), 256, 0, stream>>>(W, u2, v, blog);

    // iteration 1
    zsum_kernel<<<768, 256, 0, stream>>>(blog, zsum);
    spass_kernel<false><<<dim3(64, 12), 256, 0, stream>>>(W, u2, blog, zsum, s_part);
    squashv_kernel<true><<<512, 256, 0, stream>>>(s_part, v, 1.f);
    bpass_kernel<true><<<dim3(64, 24), 256, 0, stream>>>(W, u2, v, blog);

    // final
    zsum_kernel<<<768, 256, 0, stream>>>(blog, zsum);
    spass_kernel<false><<<dim3(64, 12), 256, 0, stream>>>(W, u2, blog, zsum, s_part);
    squashv_kernel<false><<<512, 256, 0, stream>>>(s_part, out, 1.f);
}

// Round 18
// 135.990 us; speedup vs baseline: 1.4800x; 1.0445x over previous
//
#include <hip/hip_runtime.h>
#include <math.h>

typedef __attribute__((ext_vector_type(8))) short bfrag;    // 8 bf16 = 4 VGPR
typedef __attribute__((ext_vector_type(4))) float f32x4;    // 16x16 accumulator
typedef __attribute__((ext_vector_type(16))) float f32x16;  // 32x32 accumulator
typedef __attribute__((ext_vector_type(4))) unsigned short ushort4v;
typedef unsigned short u16;

__device__ __forceinline__ float b2f(u16 h) { return __uint_as_float((unsigned)h << 16); }
__device__ __forceinline__ u16 f2b(float x) { return (u16)(__float_as_uint(x) >> 16); }

// split 8 f32 into bf16 hi + lo; (hh+hl+lh) ~ fp32. trunc8: hi only (~2^-9 rel).
__device__ __forceinline__ void split8(const float* x, bfrag& hi, bfrag& lo) {
    #pragma unroll
    for (int j = 0; j < 8; ++j) {
        unsigned xb = __float_as_uint(x[j]);
        unsigned hb = xb & 0xffff0000u;
        float lf = x[j] - __uint_as_float(hb);
        hi[j] = (short)(xb >> 16);
        lo[j] = (short)(__float_as_uint(lf) >> 16);
    }
}
__device__ __forceinline__ void trunc8(const float* x, bfrag& hi) {
    #pragma unroll
    for (int j = 0; j < 8; ++j) hi[j] = (short)(__float_as_uint(x[j]) >> 16);
}

// ---------------- front: conv1 + im2col fused, one block per batch element.
__global__ __launch_bounds__(256) void front_kernel(
    const float* __restrict__ x, const float* __restrict__ w1,
    const float* __restrict__ b1, float* __restrict__ B2) {
    __shared__ float xl[4032];
    __shared__ float wl[3456];
    __shared__ float hl[3744];
    int b = blockIdx.x, tid = threadIdx.x;
    const float* xb = x + (size_t)b * 4032;
    #pragma unroll
    for (int i = 0; i < 4; ++i) {
        int idx = tid + 256 * i;
        if (idx < 1008) *(float4*)(xl + idx * 4) = *(const float4*)(xb + idx * 4);
        if (idx < 864)  *(float4*)(wl + idx * 4) = *(const float4*)(w1 + idx * 4);
    }
    __syncthreads();
    for (int idx = tid; idx < 3744; idx += 256) {
        int oc = idx / 117, r = idx % 117;
        int oh = r / 13, ow = r % 13;
        float acc = b1[oc];
        #pragma unroll
        for (int ic = 0; ic < 3; ++ic) {
            const float* xc = xl + ic * 1344 + (oh * 3) * 42 + ow * 3;
            const float* wc = wl + (oc * 3 + ic) * 36;
            #pragma unroll
            for (int kh = 0; kh < 6; ++kh)
                #pragma unroll
                for (int kw = 0; kw < 6; ++kw)
                    acc += xc[kh * 42 + kw] * wc[kh * 6 + kw];
        }
        hl[idx] = fmaxf(acc, 0.f);
    }
    __syncthreads();
    for (int f = tid; f < 864; f += 256) {     // (ko, s)
        int ko = f / 24, s = f % 24;
        int h = s / 6, w = s % 6;
        float o8[8];
        #pragma unroll
        for (int j = 0; j < 8; ++j) {
            int k = ko * 8 + j;
            int ic = k / 9, rr = k % 9;
            int kh = rr / 3, kw = rr % 3;
            o8[j] = hl[ic * 117 + (2 * h + kh) * 13 + (2 * w + kw)];
        }
        float* dst = B2 + ((size_t)ko * 3072 + b * 24 + s) * 8;
        *(float4*)dst = *(const float4*)o8;
        *(float4*)(dst + 4) = *(const float4*)(o8 + 4);
    }
}

// ---------------- pc GEMM (MFMA) + bias + squash -> u2[i][dh][b][4]
__global__ __launch_bounds__(256) void pc_gemm_kernel(
    const float* __restrict__ wpc, const float* __restrict__ bias,
    const float* __restrict__ B2, float* __restrict__ u2) {
    int wv = threadIdx.x >> 6;
    int l = threadIdx.x & 63;
    int q = l >> 4, r16 = l & 15;
    int c2t = blockIdx.y * 4 + wv;
    int n0 = blockIdx.x * 16;
    f32x4 acc = {0.f, 0.f, 0.f, 0.f};
    const float* ap0 = wpc + (size_t)(c2t * 16 + r16) * 288 + q * 8;
    const float* bp0 = B2 + ((size_t)q * 3072 + n0 + r16) * 8;
    #pragma unroll
    for (int ks = 0; ks < 9; ++ks) {
        float av[8], bv[8];
        *(float4*)av = *(const float4*)(ap0 + ks * 32);
        *(float4*)(av + 4) = *(const float4*)(ap0 + ks * 32 + 4);
        *(float4*)bv = *(const float4*)(bp0 + (size_t)ks * 98304);
        *(float4*)(bv + 4) = *(const float4*)(bp0 + (size_t)ks * 98304 + 4);
        bfrag ahi, alo, bhi, blo;
        split8(av, ahi, alo);
        split8(bv, bhi, blo);
        acc = __builtin_amdgcn_mfma_f32_16x16x32_bf16(ahi, bhi, acc, 0, 0, 0);
        acc = __builtin_amdgcn_mfma_f32_16x16x32_bf16(ahi, blo, acc, 0, 0, 0);
        acc = __builtin_amdgcn_mfma_f32_16x16x32_bf16(alo, bhi, acc, 0, 0, 0);
    }
    int n = n0 + r16;
    int b = n / 24, s = n % 24;
    float vals[4], n2[4];
    #pragma unroll
    for (int r = 0; r < 4; ++r) {
        float xv = acc[r] + bias[c2t * 16 + q * 4 + r];
        vals[r] = xv;
        n2[r] = xv * xv;
    }
    #pragma unroll
    for (int r = 0; r < 4; ++r) {
        n2[r] += __shfl_xor(n2[r], 1, 64);
        n2[r] += __shfl_xor(n2[r], 2, 64);
        n2[r] += __shfl_xor(n2[r], 4, 64);
    }
    #pragma unroll
    for (int r = 0; r < 4; ++r) {
        int c2 = c2t * 16 + q * 4 + r;
        int cap = c2 * 3 + (s >> 3);
        int d = s & 7;
        float nr = sqrtf(n2[r]);
        u2[((size_t)(cap * 2 + (d >> 2)) * 128 + b) * 4 + (d & 3)]
            = vals[r] * nr / (1.f + n2[r]);
    }
}

// ---------------- zsum: zsum[i,b] = sum_o exp(blog[o,i,b]); 2 lanes per (i,b)
__global__ __launch_bounds__(256) void zsum_kernel(
    const u16* __restrict__ blogb, float* __restrict__ zsum) {
    int i = blockIdx.x;
    int tid = threadIdx.x;
    int b = tid >> 1, oh = tid & 1;
    const u16* src = blogb + (size_t)oh * 32 * 98304 + (size_t)i * 128 + b;
    float sum = 0.f;
    #pragma unroll
    for (int o = 0; o < 32; ++o) sum += __expf(b2f(src[(size_t)o * 98304]));
    sum += __shfl_xor(sum, 1, 64);
    if (!oh) zsum[i * 128 + b] = sum;
}

// ---------------- s-pass: 64-cap tiles; W pre-split to bf16 hi/lo in LDS.
template <bool UNIFORM>
__global__ __launch_bounds__(256, 4) void spass_kernel(
    const float* __restrict__ W, const float* __restrict__ u2,
    const u16* __restrict__ blogb, const float* __restrict__ zsum,
    u16* __restrict__ s_part) {
    int o = blockIdx.x;
    int it = blockIdx.y;       // 0..11 (64 caps)
    int tid = threadIdx.x;
    int wv = tid >> 6;
    int l = tid & 63;
    int q = l >> 4, r16 = l & 15;
    int i0 = it * 64;
    __shared__ unsigned short whi[64 * 136];
    __shared__ unsigned short wlo[64 * 136];

    float4 ua[3][2][2];
    float blv[3][2], zv[3][2];
    auto issue = [&](int s, int buf) {
        int cap = i0 + s * 4 + q;
        #pragma unroll
        for (int m = 0; m < 2; ++m) {
            int b = wv * 32 + m * 16 + r16;
            ua[buf][m][0] = *(const float4*)(u2 + ((size_t)(cap * 2 + 0) * 128 + b) * 4);
            ua[buf][m][1] = *(const float4*)(u2 + ((size_t)(cap * 2 + 1) * 128 + b) * 4);
            if (!UNIFORM) {
                blv[buf][m] = b2f(blogb[((size_t)o * 768 + cap) * 128 + b]);
                zv[buf][m]  = zsum[cap * 128 + b];
            }
        }
    };

    issue(0, 0);
    issue(1, 1);
    #pragma unroll
    for (int itr = 0; itr < 8; ++itr) {
        int F = tid + 256 * itr;     // 0..2047 float4s
        int cap = F >> 5, slot = F & 31;
        float4 t4 = *(const float4*)(W + ((size_t)(i0 + cap) * 64 + o) * 128 + slot * 4);
        ushort4v h4, l4;
        float tf[4] = {t4.x, t4.y, t4.z, t4.w};
        #pragma unroll
        for (int j = 0; j < 4; ++j) {
            unsigned xb = __float_as_uint(tf[j]);
            float lf = tf[j] - __uint_as_float(xb & 0xffff0000u);
            h4[j] = (unsigned short)(xb >> 16);
            l4[j] = (unsigned short)(__float_as_uint(lf) >> 16);
        }
        *(ushort4v*)(whi + cap * 136 + slot * 4) = h4;
        *(ushort4v*)(wlo + cap * 136 + slot * 4) = l4;
    }
    __syncthreads();

    f32x4 acc0 = {0.f, 0.f, 0.f, 0.f};
    f32x4 acc1 = {0.f, 0.f, 0.f, 0.f};
    #pragma unroll
    for (int s = 0; s < 16; ++s) {
        int cur = s % 3;
        if (s < 14) issue(s + 2, (s + 2) % 3);
        int wrow = (s * 4 + q) * 136 + r16 * 8;
        bfrag bhi = *(const bfrag*)(whi + wrow);
        bfrag blo = *(const bfrag*)(wlo + wrow);
        #pragma unroll
        for (int m = 0; m < 2; ++m) {
            float uv[8];
            *(float4*)(uv) = ua[cur][m][0];
            *(float4*)(uv + 4) = ua[cur][m][1];
            if (!UNIFORM) {
                float c = __expf(blv[cur][m]) / zv[cur][m];
                #pragma unroll
                for (int j = 0; j < 8; ++j) uv[j] *= c;
            }
            bfrag ahi;
            trunc8(uv, ahi);
            if (m == 0) {
                acc0 = __builtin_amdgcn_mfma_f32_16x16x32_bf16(ahi, bhi, acc0, 0, 0, 0);
                acc0 = __builtin_amdgcn_mfma_f32_16x16x32_bf16(ahi, blo, acc0, 0, 0, 0);
            } else {
                acc1 = __builtin_amdgcn_mfma_f32_16x16x32_bf16(ahi, bhi, acc1, 0, 0, 0);
                acc1 = __builtin_amdgcn_mfma_f32_16x16x32_bf16(ahi, blo, acc1, 0, 0, 0);
            }
        }
    }
    #pragma unroll
    for (int reg = 0; reg < 4; ++reg) {
        int b0 = wv * 32 + q * 4 + reg;
        s_part[(((size_t)it * 128 + b0) * 64 + o) * 16 + r16] = f2b(acc0[reg]);
        s_part[(((size_t)it * 128 + b0 + 16) * 64 + o) * 16 + r16] = f2b(acc1[reg]);
    }
}

// ---------------- reduce 12 bf16 partials + squash -> v ([b][o][k] or [o][b][k])
template <bool TRANSPOSED>
__global__ __launch_bounds__(256) void squashv_kernel(
    const u16* __restrict__ s_part, float* __restrict__ v, float scale) {
    int idx = blockIdx.x * 256 + threadIdx.x;
    float acc = 0.f;
    #pragma unroll
    for (int it = 0; it < 12; ++it) acc += b2f(s_part[(size_t)it * 131072 + idx]);
    acc *= scale;
    float n2 = acc * acc;
    n2 += __shfl_xor(n2, 1, 64);
    n2 += __shfl_xor(n2, 2, 64);
    n2 += __shfl_xor(n2, 4, 64);
    n2 += __shfl_xor(n2, 8, 64);
    float n = sqrtf(n2);
    float val = acc * n / (1.f + n2);
    if (TRANSPOSED) {
        int k = idx & 15, o = (idx >> 4) & 63, b = idx >> 10;
        v[((size_t)o * 128 + b) * 16 + k] = val;
    } else {
        v[idx] = val;
    }
}

// ---------------- b-pass: blog(bf16) (+)= sum_d u*(W x v); v truncated (2-term)
template <bool ACCUM>
__global__ __launch_bounds__(256, 4) void bpass_kernel(
    const float* __restrict__ W, const float* __restrict__ u2,
    const float* __restrict__ v_t, u16* __restrict__ blogb) {
    int o = blockIdx.x, it = blockIdx.y;   // it: 0..23 (32 caps)
    int tid = threadIdx.x;
    int wv = tid >> 6;
    int l = tid & 63;
    int r = l & 31;
    int kh = l >> 5;
    int capB = it * 32;
    __shared__ float wl[32 * 164];
    #pragma unroll
    for (int itr = 0; itr < 4; ++itr) {
        int F = tid + 256 * itr;
        int cap = F >> 5, slot = F & 31;
        int k = slot >> 1, dh = slot & 1;
        float4 t4 = *(const float4*)(W + ((size_t)(capB + cap) * 64 + o) * 128 + k * 8 + dh * 4);
        float* dst = wl + cap * 164 + (dh * 4) * 20 + k;
        dst[0] = t4.x; dst[20] = t4.y; dst[40] = t4.z; dst[60] = t4.w;
    }
    bfrag vt[4];
    #pragma unroll
    for (int nt = 0; nt < 4; ++nt) {
        const float* vp = v_t + ((size_t)o * 128 + nt * 32 + r) * 16 + kh * 8;
        float vv8[8];
        *(float4*)(vv8) = *(const float4*)vp;
        *(float4*)(vv8 + 4) = *(const float4*)(vp + 4);
        trunc8(vv8, vt[nt]);
    }
    __syncthreads();
    #pragma unroll
    for (int mt = 0; mt < 2; ++mt) {
        int cl = wv * 8 + mt * 4 + (r >> 3);
        const float* ap = wl + cl * 164 + (r & 7) * 20 + kh * 8;
        float a8[8];
        *(float4*)(a8) = *(const float4*)ap;
        *(float4*)(a8 + 4) = *(const float4*)(ap + 4);
        int capg = capB + wv * 8 + mt * 4;
        int gw = kh * 2;
        float prevv[4][2];
        if (ACCUM) {
            #pragma unroll
            for (int nt = 0; nt < 4; ++nt) {
                int b = nt * 32 + r;
                #pragma unroll
                for (int gg = 0; gg < 2; ++gg)
                    prevv[nt][gg] = b2f(blogb[((size_t)o * 768 + capg + gw + gg) * 128 + b]);
            }
        }
        float4 u4b[2][4];
        #pragma unroll
        for (int g = 0; g < 4; ++g)
            u4b[0][g] = *(const float4*)(u2 + ((size_t)((capg + g) * 2 + kh) * 128 + r) * 4);
        bfrag ahi, alo;
        split8(a8, ahi, alo);
        #pragma unroll
        for (int nt = 0; nt < 4; ++nt) {
            int cur = nt & 1;
            if (nt < 3) {
                int bn = (nt + 1) * 32 + r;
                #pragma unroll
                for (int g = 0; g < 4; ++g)
                    u4b[cur ^ 1][g] = *(const float4*)(u2 + ((size_t)((capg + g) * 2 + kh) * 128 + bn) * 4);
            }
            int b = nt * 32 + r;
            f32x16 acc;
            #pragma unroll
            for (int z = 0; z < 16; ++z) acc[z] = 0.f;
            acc = __builtin_amdgcn_mfma_f32_32x32x16_bf16(ahi, vt[nt], acc, 0, 0, 0);
            acc = __builtin_amdgcn_mfma_f32_32x32x16_bf16(alo, vt[nt], acc, 0, 0, 0);
            float full[4];
            #pragma unroll
            for (int g = 0; g < 4; ++g) {
                float part = u4b[cur][g].x * acc[g * 4 + 0] + u4b[cur][g].y * acc[g * 4 + 1]
                           + u4b[cur][g].z * acc[g * 4 + 2] + u4b[cur][g].w * acc[g * 4 + 3];
                full[g] = part + __shfl_xor(part, 32, 64);
            }
            #pragma unroll
            for (int gg = 0; gg < 2; ++gg) {
                int g = gw + gg;
                size_t bi = ((size_t)o * 768 + capg + g) * 128 + b;
                blogb[bi] = f2b((ACCUM ? prevv[nt][gg] : 0.f) + full[g]);
            }
        }
    }
}

extern "C" void kernel_launch(void* const* d_in, const int* in_sizes, int n_in,
                              void* d_out, int out_size, void* d_ws, size_t ws_size,
                              hipStream_t stream) {
    const float* x  = (const float*)d_in[0];
    const float* w1 = (const float*)d_in[1];
    const float* b1 = (const float*)d_in[2];
    const float* wp = (const float*)d_in[3];
    const float* bp = (const float*)d_in[4];
    const float* W  = (const float*)d_in[5];
    float* out = (float*)d_out;
    float* ws = (float*)d_ws;

    float* u2     = ws;                        // 786432 floats
    u16*   blogb  = (u16*)(ws + 786432);       // 6291456 u16 (3145728 float slots)
    float* zsum   = ws + 3932160;              // 98304
    float* v      = ws + 4030464;              // 131072
    u16*   s_part = (u16*)(ws + 4161536);      // 1572864 u16 (786432 float slots)
    float* B2     = ws + 4947968;              // 884736

    front_kernel<<<128, 256, 0, stream>>>(x, w1, b1, B2);
    pc_gemm_kernel<<<dim3(192, 4), 256, 0, stream>>>(wp, bp, B2, u2);

    // iteration 0: c uniform (1/64 folded into squash scale)
    spass_kernel<true><<<dim3(64, 12), 256, 0, stream>>>(W, u2, nullptr, nullptr, s_part);
    squashv_kernel<true><<<512, 256, 0, stream>>>(s_part, v, 1.f / 64.f);
    bpass_kernel<false><<<dim3(64, 24), 256, 0, stream>>>(W, u2, v, blogb);

    // iteration 1
    zsum_kernel<<<768, 256, 0, stream>>>(blogb, zsum);
    spass_kernel<false><<<dim3(64, 12), 256, 0, stream>>>(W, u2, blogb, zsum, s_part);
    squashv_kernel<true><<<512, 256, 0, stream>>>(s_part, v, 1.f);
    bpass_kernel<true><<<dim3(64, 24), 256, 0, stream>>>(W, u2, v, blogb);

    // final
    zsum_kernel<<<768, 256, 0, stream>>>(blogb, zsum);
    spass_kernel<false><<<dim3(64, 12), 256, 0, stream>>>(W, u2, blogb, zsum, s_part);
    squashv_kernel<false><<<512, 256, 0, stream>>>(s_part, out, 1.f);
}